// Round 1
// baseline (595.860 us; speedup 1.0000x reference)
//
#include <hip/hip_runtime.h>
#include <hip/hip_bf16.h>

// DeepFM constants
#define BATCH 16384
#define FIELD 39
#define EMB 32
#define DIN (FIELD * EMB)   // 1248
#define HID 400
#define DCAT (FIELD + EMB + HID) // 471

// ---------------------------------------------------------------------------
// Kernel 1: per-row embedding gather + first_order + second_order.
// One 256-thread block per batch row.
//   emb[r][f*32+j] = emb_table[idx[r][f]][j] * val[r][f]   -> ws (fp32)
//   first_order[r][f] = bias_table[idx[r][f]] * val[r][f]  -> d_out region
//   second_order[r][j] = 0.5*(sum_f emb)^2 - 0.5*sum_f emb^2
// ---------------------------------------------------------------------------
__global__ __launch_bounds__(256) void gather_fm_kernel(
    const int* __restrict__ feat_index,
    const float* __restrict__ feat_value,
    const float* __restrict__ emb_table,
    const float* __restrict__ bias_table,
    float* __restrict__ emb_ws,        // BATCH x DIN
    float* __restrict__ first_order,   // BATCH x FIELD
    float* __restrict__ second_order)  // BATCH x EMB
{
    __shared__ int   s_idx[FIELD];
    __shared__ float s_val[FIELD];
    __shared__ float s_emb[FIELD][EMB];  // 4992 B

    const int r = blockIdx.x;
    const int t = threadIdx.x;

    if (t < FIELD) {
        int   idx = feat_index[r * FIELD + t];
        float val = feat_value[r * FIELD + t];
        s_idx[t] = idx;
        s_val[t] = val;
        // first order: bias gather (scattered 4B loads, 39 per row)
        first_order[r * FIELD + t] = bias_table[idx] * val;
    }
    __syncthreads();

    // gather embedding rows; lanes sweep j fastest -> 128B coalesced per field
    for (int e = t; e < DIN; e += 256) {
        const int f = e >> 5;
        const int j = e & 31;
        float v = emb_table[(size_t)s_idx[f] * EMB + j] * s_val[f];
        s_emb[f][j] = v;
        emb_ws[(size_t)r * DIN + e] = v;
    }
    __syncthreads();

    // second order: one thread per embed dim, serial over 39 fields (LDS, conflict-free)
    if (t < EMB) {
        float s = 0.f, sq = 0.f;
        #pragma unroll
        for (int f = 0; f < FIELD; ++f) {
            float v = s_emb[f][t];
            s  += v;
            sq += v * v;
        }
        second_order[r * EMB + t] = 0.5f * (s * s - sq);
    }
}

// ---------------------------------------------------------------------------
// Kernel 2/3: fp32 NT-GEMM  C[m][n] = relu( sum_k A[m][k]*Bw[n][k] + bias[n] )
// A: M x K row-major, Bw: N x K row-major (both K-contiguous -> coalesced).
// 64x64 C-tile per 256-thread block, BK=16, 4x4 micro-tile per thread.
// M, K multiples of 16/64; N guarded (N=400).
// ---------------------------------------------------------------------------
__global__ __launch_bounds__(256) void gemm_nt_relu(
    const float* __restrict__ A,
    const float* __restrict__ Bw,
    const float* __restrict__ bias,
    float* __restrict__ C,
    int M, int N, int K)
{
    constexpr int BM = 64, BN = 64, BK = 16;
    __shared__ __align__(16) float As[BK][BM + 4];  // stored transposed: As[k][m]
    __shared__ __align__(16) float Bs[BK][BN + 4];  // Bs[k][n]

    const int tid = threadIdx.x;
    const int m0 = blockIdx.x * BM;
    const int n0 = blockIdx.y * BN;

    // micro-tile coords: consecutive tid -> consecutive columns (coalesced C stores)
    const int tx = tid & 15;        // column group
    const int ty = tid >> 4;        // row group
    const int col0 = tx * 4;
    const int row0 = ty * 4;

    // staging: each thread loads one float4 of A and of Bw per k-step
    const int lrow = tid >> 2;          // 0..63
    const int lk4  = (tid & 3) * 4;     // 0,4,8,12

    float acc[4][4] = {};

    for (int k0 = 0; k0 < K; k0 += BK) {
        float4 a4 = *(const float4*)(A + (size_t)(m0 + lrow) * K + k0 + lk4);
        float4 b4 = make_float4(0.f, 0.f, 0.f, 0.f);
        if (n0 + lrow < N)
            b4 = *(const float4*)(Bw + (size_t)(n0 + lrow) * K + k0 + lk4);

        As[lk4 + 0][lrow] = a4.x; As[lk4 + 1][lrow] = a4.y;
        As[lk4 + 2][lrow] = a4.z; As[lk4 + 3][lrow] = a4.w;
        Bs[lk4 + 0][lrow] = b4.x; Bs[lk4 + 1][lrow] = b4.y;
        Bs[lk4 + 2][lrow] = b4.z; Bs[lk4 + 3][lrow] = b4.w;
        __syncthreads();

        #pragma unroll
        for (int kk = 0; kk < BK; ++kk) {
            float4 av = *(const float4*)&As[kk][row0];  // rows (broadcast across lanes)
            float4 bv = *(const float4*)&Bs[kk][col0];  // cols (2-way bank alias, free)
            float a[4] = {av.x, av.y, av.z, av.w};
            float b[4] = {bv.x, bv.y, bv.z, bv.w};
            #pragma unroll
            for (int i = 0; i < 4; ++i)
                #pragma unroll
                for (int j = 0; j < 4; ++j)
                    acc[i][j] = fmaf(a[i], b[j], acc[i][j]);
        }
        __syncthreads();
    }

    #pragma unroll
    for (int i = 0; i < 4; ++i) {
        const int row = m0 + row0 + i;
        #pragma unroll
        for (int j = 0; j < 4; ++j) {
            const int col = n0 + col0 + j;
            if (col < N) {
                float v = acc[i][j] + bias[col];
                C[(size_t)row * N + col] = v > 0.f ? v : 0.f;
            }
        }
    }
}

// ---------------------------------------------------------------------------
// Kernel 4: final dot over the 471-wide concat. One wave (64 lanes) per row.
// ---------------------------------------------------------------------------
__global__ __launch_bounds__(256) void final_kernel(
    const float* __restrict__ fo,   // BATCH x FIELD
    const float* __restrict__ so,   // BATCH x EMB
    const float* __restrict__ dy,   // BATCH x HID
    const float* __restrict__ fW,   // DCAT
    const float* __restrict__ fb,   // 1
    float* __restrict__ out)        // BATCH
{
    const int lane = threadIdx.x & 63;
    const int wave = threadIdx.x >> 6;
    const int r = blockIdx.x * 4 + wave;

    float s = 0.f;
    if (lane < FIELD)
        s += fo[(size_t)r * FIELD + lane] * fW[lane];
    if (lane < EMB)
        s += so[(size_t)r * EMB + lane] * fW[FIELD + lane];
    for (int e = lane; e < HID; e += 64)
        s += dy[(size_t)r * HID + e] * fW[FIELD + EMB + e];

    #pragma unroll
    for (int off = 32; off > 0; off >>= 1)
        s += __shfl_down(s, off, 64);

    if (lane == 0)
        out[r] = s + fb[0];
}

// ---------------------------------------------------------------------------
extern "C" void kernel_launch(void* const* d_in, const int* in_sizes, int n_in,
                              void* d_out, int out_size, void* d_ws, size_t ws_size,
                              hipStream_t stream)
{
    const int*   feat_index = (const int*)d_in[0];
    const float* feat_value = (const float*)d_in[1];
    const float* emb_table  = (const float*)d_in[2];
    const float* bias_table = (const float*)d_in[3];
    const float* W1         = (const float*)d_in[4];
    const float* b1         = (const float*)d_in[5];
    const float* W2         = (const float*)d_in[6];
    const float* b2         = (const float*)d_in[7];
    const float* fW         = (const float*)d_in[8];
    const float* fb         = (const float*)d_in[9];

    float* out = (float*)d_out;
    // d_out layout: [output (B)] [first_order (B*39)] [second_order (B*32)] [deep_y (B*400)]
    float* out0 = out;
    float* fo   = out + BATCH;
    float* so   = out + (size_t)BATCH * (1 + FIELD);
    float* dy   = out + (size_t)BATCH * (1 + FIELD + EMB);

    // workspace: emb (B x 1248 fp32, 81.8 MB) then h1 (B x 400 fp32, 26.2 MB)
    float* emb_ws = (float*)d_ws;
    float* h1     = emb_ws + (size_t)BATCH * DIN;

    gather_fm_kernel<<<BATCH, 256, 0, stream>>>(
        feat_index, feat_value, emb_table, bias_table, emb_ws, fo, so);

    dim3 grid_g(BATCH / 64, (HID + 63) / 64);  // 256 x 7
    gemm_nt_relu<<<grid_g, 256, 0, stream>>>(emb_ws, W1, b1, h1, BATCH, HID, DIN);
    gemm_nt_relu<<<grid_g, 256, 0, stream>>>(h1, W2, b2, dy, BATCH, HID, HID);

    final_kernel<<<BATCH / 4, 256, 0, stream>>>(fo, so, dy, fW, fb, out0);
}

// Round 2
// 318.500 us; speedup vs baseline: 1.8708x; 1.8708x over previous
//
#include <hip/hip_runtime.h>
#include <hip/hip_bf16.h>

// DeepFM constants
#define BATCH 16384
#define FIELD 39
#define EMB 32
#define DIN (FIELD * EMB)   // 1248
#define HID 400
#define DCAT (FIELD + EMB + HID) // 471

typedef __attribute__((ext_vector_type(8))) short short8;   // 8 bf16 = 4 VGPRs
typedef __attribute__((ext_vector_type(4))) float float4v;  // MFMA C/D

static __device__ __forceinline__ unsigned short f2bf(float f) {
    __hip_bfloat16 h = __float2bfloat16(f);  // RNE
    return *(unsigned short*)&h;
}

// ---------------------------------------------------------------------------
// Kernel 1: per-row embedding gather + first_order + second_order.
// emb written as bf16 (GEMM1 input); second_order computed in fp32 from LDS.
// ---------------------------------------------------------------------------
__global__ __launch_bounds__(256) void gather_fm_kernel(
    const int* __restrict__ feat_index,
    const float* __restrict__ feat_value,
    const float* __restrict__ emb_table,
    const float* __restrict__ bias_table,
    unsigned short* __restrict__ emb_ws,  // BATCH x DIN (bf16)
    float* __restrict__ first_order,      // BATCH x FIELD
    float* __restrict__ second_order)     // BATCH x EMB
{
    __shared__ int   s_idx[FIELD];
    __shared__ float s_val[FIELD];
    __shared__ float s_emb[FIELD][EMB];

    const int r = blockIdx.x;
    const int t = threadIdx.x;

    if (t < FIELD) {
        int   idx = feat_index[r * FIELD + t];
        float val = feat_value[r * FIELD + t];
        s_idx[t] = idx;
        s_val[t] = val;
        first_order[r * FIELD + t] = bias_table[idx] * val;
    }
    __syncthreads();

    for (int e = t; e < DIN; e += 256) {
        const int f = e >> 5;
        const int j = e & 31;
        float v = emb_table[(size_t)s_idx[f] * EMB + j] * s_val[f];
        s_emb[f][j] = v;
        emb_ws[(size_t)r * DIN + e] = f2bf(v);
    }
    __syncthreads();

    if (t < EMB) {
        float s = 0.f, sq = 0.f;
        #pragma unroll
        for (int f = 0; f < FIELD; ++f) {
            float v = s_emb[f][t];
            s  += v;
            sq += v * v;
        }
        second_order[r * EMB + t] = 0.5f * (s * s - sq);
    }
}

// ---------------------------------------------------------------------------
// Weight fp32 -> bf16 conversion (W1 then W2, one flat kernel)
// ---------------------------------------------------------------------------
__global__ __launch_bounds__(256) void cvt_weights(
    const float* __restrict__ W1, const float* __restrict__ W2,
    unsigned short* __restrict__ W1b, unsigned short* __restrict__ W2b,
    int n1, int n2)
{
    int i = blockIdx.x * 256 + threadIdx.x;
    if (i < n1)           W1b[i]      = f2bf(W1[i]);
    else if (i < n1 + n2) W2b[i - n1] = f2bf(W2[i - n1]);
}

// ---------------------------------------------------------------------------
// MFMA NT-GEMM: C[m][n] = relu( sum_k A[m][k]*Bw[n][k] + bias[n] )
// A: MxK bf16 row-major; Bw: NxK bf16 row-major (both K-contiguous).
// 128x128 tile / 256 threads (4 waves, 64x64 each, 4x4 16x16 fragments), BK=32.
// K handled at 8-element granularity (zero-fill); N guarded.
// Fragment layouts (m89/m120-verified):
//   A: lane holds A[m=lane&15][k=quad*8+j]; B mirrored; D: col=lane&15, row=quad*4+reg.
// ---------------------------------------------------------------------------
template<bool OUT_BF16>
__global__ __launch_bounds__(256) void gemm_mfma_nt(
    const unsigned short* __restrict__ A,
    const unsigned short* __restrict__ Bw,
    const float* __restrict__ bias,
    void* __restrict__ Cp,
    int M, int N, int K)
{
    constexpr int BM = 128, BN = 128, BK = 32;
    constexpr int LDT = BK + 8;  // 40 bf16 = 80 B row stride (16B-aligned, 2-way bank alias)
    __shared__ __align__(16) unsigned short As[BM][LDT];
    __shared__ __align__(16) unsigned short Bs[BN][LDT];

    const int tid  = threadIdx.x;
    const int wave = tid >> 6;
    const int lane = tid & 63;
    const int quad = lane >> 4;
    const int l16  = lane & 15;
    const int wm = (wave & 1) * 64;
    const int wn = (wave >> 1) * 64;
    const int m0 = blockIdx.x * BM;
    const int n0 = blockIdx.y * BN;

    const int srow   = tid >> 2;        // 0..63
    const int schunk = (tid & 3) * 8;   // k-offset 0,8,16,24

    float4v acc[4][4];
    #pragma unroll
    for (int i = 0; i < 4; ++i)
        #pragma unroll
        for (int j = 0; j < 4; ++j)
            acc[i][j] = (float4v)(0.f);

    for (int k0 = 0; k0 < K; k0 += BK) {
        const bool kin = (k0 + schunk) < K;   // K multiple of 8 -> chunk all-in or all-out
        #pragma unroll
        for (int p = 0; p < 2; ++p) {
            const int row = p * 64 + srow;
            short8 av = (short8)0;
            if (kin)
                av = *(const short8*)(A + (size_t)(m0 + row) * K + k0 + schunk);
            *(short8*)(&As[row][schunk]) = av;
            short8 bv = (short8)0;
            if (kin && (n0 + row) < N)
                bv = *(const short8*)(Bw + (size_t)(n0 + row) * K + k0 + schunk);
            *(short8*)(&Bs[row][schunk]) = bv;
        }
        __syncthreads();

        short8 af[4], bf[4];
        #pragma unroll
        for (int i = 0; i < 4; ++i)
            af[i] = *(const short8*)(&As[wm + i * 16 + l16][quad * 8]);
        #pragma unroll
        for (int j = 0; j < 4; ++j)
            bf[j] = *(const short8*)(&Bs[wn + j * 16 + l16][quad * 8]);

        #pragma unroll
        for (int i = 0; i < 4; ++i)
            #pragma unroll
            for (int j = 0; j < 4; ++j)
                acc[i][j] = __builtin_amdgcn_mfma_f32_16x16x32_bf16(
                    af[i], bf[j], acc[i][j], 0, 0, 0);
        __syncthreads();
    }

    #pragma unroll
    for (int i = 0; i < 4; ++i) {
        const int rbase = m0 + wm + i * 16 + quad * 4;
        #pragma unroll
        for (int j = 0; j < 4; ++j) {
            const int col = n0 + wn + j * 16 + l16;
            if (col < N) {
                const float bv = bias[col];
                #pragma unroll
                for (int r2 = 0; r2 < 4; ++r2) {
                    float v = acc[i][j][r2] + bv;
                    v = v > 0.f ? v : 0.f;
                    if (OUT_BF16)
                        ((unsigned short*)Cp)[(size_t)(rbase + r2) * N + col] = f2bf(v);
                    else
                        ((float*)Cp)[(size_t)(rbase + r2) * N + col] = v;
                }
            }
        }
    }
}

// ---------------------------------------------------------------------------
// Final dot over the 471-wide concat. One wave per row.
// ---------------------------------------------------------------------------
__global__ __launch_bounds__(256) void final_kernel(
    const float* __restrict__ fo,
    const float* __restrict__ so,
    const float* __restrict__ dy,
    const float* __restrict__ fW,
    const float* __restrict__ fb,
    float* __restrict__ out)
{
    const int lane = threadIdx.x & 63;
    const int wave = threadIdx.x >> 6;
    const int r = blockIdx.x * 4 + wave;

    float s = 0.f;
    if (lane < FIELD)
        s += fo[(size_t)r * FIELD + lane] * fW[lane];
    if (lane < EMB)
        s += so[(size_t)r * EMB + lane] * fW[FIELD + lane];
    for (int e = lane; e < HID; e += 64)
        s += dy[(size_t)r * HID + e] * fW[FIELD + EMB + e];

    #pragma unroll
    for (int off = 32; off > 0; off >>= 1)
        s += __shfl_down(s, off, 64);

    if (lane == 0)
        out[r] = s + fb[0];
}

// ---------------------------------------------------------------------------
extern "C" void kernel_launch(void* const* d_in, const int* in_sizes, int n_in,
                              void* d_out, int out_size, void* d_ws, size_t ws_size,
                              hipStream_t stream)
{
    const int*   feat_index = (const int*)d_in[0];
    const float* feat_value = (const float*)d_in[1];
    const float* emb_table  = (const float*)d_in[2];
    const float* bias_table = (const float*)d_in[3];
    const float* W1         = (const float*)d_in[4];
    const float* b1         = (const float*)d_in[5];
    const float* W2         = (const float*)d_in[6];
    const float* b2         = (const float*)d_in[7];
    const float* fW         = (const float*)d_in[8];
    const float* fb         = (const float*)d_in[9];

    float* out = (float*)d_out;
    float* out0 = out;
    float* fo   = out + BATCH;
    float* so   = out + (size_t)BATCH * (1 + FIELD);
    float* dy   = out + (size_t)BATCH * (1 + FIELD + EMB);

    // workspace (bf16 regions, all 16B-aligned):
    //   emb  : BATCH*DIN   = 40.9 MB
    //   h1   : BATCH*HID   = 13.1 MB
    //   W1b  : 400*1248    ~ 1.0 MB
    //   W2b  : 400*400     ~ 0.32 MB
    unsigned short* emb_ws = (unsigned short*)d_ws;
    unsigned short* h1     = emb_ws + (size_t)BATCH * DIN;
    unsigned short* W1b    = h1 + (size_t)BATCH * HID;
    unsigned short* W2b    = W1b + (size_t)HID * DIN;

    const int n1 = HID * DIN, n2 = HID * HID;
    cvt_weights<<<(n1 + n2 + 255) / 256, 256, 0, stream>>>(W1, W2, W1b, W2b, n1, n2);

    gather_fm_kernel<<<BATCH, 256, 0, stream>>>(
        feat_index, feat_value, emb_table, bias_table, emb_ws, fo, so);

    dim3 grid_g(BATCH / 128, (HID + 127) / 128);  // 128 x 4
    gemm_mfma_nt<true ><<<grid_g, 256, 0, stream>>>(emb_ws, W1b, b1, h1, BATCH, HID, DIN);
    gemm_mfma_nt<false><<<grid_g, 256, 0, stream>>>(h1,     W2b, b2, dy, BATCH, HID, HID);

    final_kernel<<<BATCH / 4, 256, 0, stream>>>(fo, so, dy, fW, fb, out0);
}

// Round 3
// 278.172 us; speedup vs baseline: 2.1421x; 1.1450x over previous
//
#include <hip/hip_runtime.h>
#include <hip/hip_bf16.h>

// DeepFM constants
#define BATCH 16384
#define FIELD 39
#define EMB 32
#define DIN (FIELD * EMB)      // 1248
#define HID 400
#define NPAD 512               // padded N for both GEMMs (no guards in K-loop)
#define K2P 416                // padded K for GEMM2 (13 * 32)

typedef __attribute__((ext_vector_type(8))) short short8;   // 8 bf16 = 4 VGPRs
typedef __attribute__((ext_vector_type(4))) float float4v;  // MFMA C/D

static __device__ __forceinline__ unsigned short f2bf(float f) {
    __hip_bfloat16 h = __float2bfloat16(f);  // RNE
    return *(unsigned short*)&h;
}

// ---------------------------------------------------------------------------
// Kernel 1: wave-per-row embedding gather + first_order + second_order.
// No __syncthreads; FM sums via shfl_xor; emb written packed bf16.
// Lane l: field-sub = l>>3 (8 fields/step), dim-quad = (l&7)*4 (float4 reads).
// ---------------------------------------------------------------------------
__global__ __launch_bounds__(256) void gather_fm_kernel(
    const int* __restrict__ feat_index,
    const float* __restrict__ feat_value,
    const float* __restrict__ emb_table,
    const float* __restrict__ bias_table,
    unsigned short* __restrict__ emb_ws,  // BATCH x DIN (bf16)
    float* __restrict__ first_order,      // BATCH x FIELD
    float* __restrict__ second_order)     // BATCH x EMB
{
    const int lane = threadIdx.x & 63;
    const int wave = threadIdx.x >> 6;
    const int r = blockIdx.x * 4 + wave;

    int   idx0 = 0;
    float val0 = 0.f;
    if (lane < FIELD) {
        idx0 = feat_index[r * FIELD + lane];
        val0 = feat_value[r * FIELD + lane];
        first_order[r * FIELD + lane] = bias_table[idx0] * val0;
    }

    const int fsub = lane >> 3;       // 0..7
    const int j4   = (lane & 7) * 4;  // dim quad offset

    float sx = 0.f, sy = 0.f, sz = 0.f, sw = 0.f;
    float qx = 0.f, qy = 0.f, qz = 0.f, qw = 0.f;

    #pragma unroll
    for (int step = 0; step < 5; ++step) {
        const int  f  = step * 8 + fsub;        // 0..39
        const int  fi = __shfl(idx0, f, 64);
        const float fv = __shfl(val0, f, 64);
        const bool ok = (f < FIELD);
        float4 e4 = make_float4(0.f, 0.f, 0.f, 0.f);
        if (ok) {
            float4 t = *(const float4*)(emb_table + (size_t)fi * EMB + j4);
            e4.x = t.x * fv; e4.y = t.y * fv; e4.z = t.z * fv; e4.w = t.w * fv;
            // packed bf16 write: e = f*32 + j4 = step*256 + lane*4 (contiguous)
            uint2 pk;
            pk.x = (unsigned)f2bf(e4.x) | ((unsigned)f2bf(e4.y) << 16);
            pk.y = (unsigned)f2bf(e4.z) | ((unsigned)f2bf(e4.w) << 16);
            *(uint2*)(emb_ws + (size_t)r * DIN + step * 256 + lane * 4) = pk;
        }
        sx += e4.x; sy += e4.y; sz += e4.z; sw += e4.w;
        qx += e4.x * e4.x; qy += e4.y * e4.y; qz += e4.z * e4.z; qw += e4.w * e4.w;
    }

    // reduce over the 8 field-sub groups (lanes differing in bits 3..5)
    #pragma unroll
    for (int d = 8; d < 64; d <<= 1) {
        sx += __shfl_xor(sx, d, 64); sy += __shfl_xor(sy, d, 64);
        sz += __shfl_xor(sz, d, 64); sw += __shfl_xor(sw, d, 64);
        qx += __shfl_xor(qx, d, 64); qy += __shfl_xor(qy, d, 64);
        qz += __shfl_xor(qz, d, 64); qw += __shfl_xor(qw, d, 64);
    }

    if (lane < 8) {
        float4 so4;
        so4.x = 0.5f * (sx * sx - qx);
        so4.y = 0.5f * (sy * sy - qy);
        so4.z = 0.5f * (sz * sz - qz);
        so4.w = 0.5f * (sw * sw - qw);
        *(float4*)(second_order + (size_t)r * EMB + lane * 4) = so4;
    }
}

// ---------------------------------------------------------------------------
// Weight conversion + zero-padding:
//   W1b : NPAD x DIN  (rows >=400 zero)
//   W2b : NPAD x K2P  (rows >=400 or cols >=400 zero)
//   b1p, b2p : NPAD   (entries >=400 zero)
// ---------------------------------------------------------------------------
__global__ __launch_bounds__(256) void cvt_weights(
    const float* __restrict__ W1, const float* __restrict__ W2,
    const float* __restrict__ b1, const float* __restrict__ b2,
    unsigned short* __restrict__ W1b, unsigned short* __restrict__ W2b,
    float* __restrict__ b1p, float* __restrict__ b2p)
{
    const int n1p = NPAD * DIN;
    const int n2p = NPAD * K2P;
    int i = blockIdx.x * 256 + threadIdx.x;
    if (i < n1p) {
        int row = i / DIN, col = i - row * DIN;
        W1b[i] = (row < HID) ? f2bf(W1[row * DIN + col]) : (unsigned short)0;
    } else if (i < n1p + n2p) {
        int j = i - n1p;
        int row = j / K2P, col = j - row * K2P;
        W2b[j] = (row < HID && col < HID) ? f2bf(W2[row * HID + col]) : (unsigned short)0;
    } else if (i < n1p + n2p + NPAD) {
        int k = i - n1p - n2p;
        b1p[k] = (k < HID) ? b1[k] : 0.f;
    } else if (i < n1p + n2p + 2 * NPAD) {
        int k = i - n1p - n2p - NPAD;
        b2p[k] = (k < HID) ? b2[k] : 0.f;
    }
}

// ---------------------------------------------------------------------------
// m97-pattern MFMA NT-GEMM: C = relu(A * Bw^T + bias)
// A: M x K bf16 (row stride lda), Bw: NPAD x K bf16 (row stride ldb, padded,
// unguarded). 128x128 tile / 256 threads / 4 waves (64x64 each), BK=32.
// Staging via global_load_lds width=16 into unpadded LDS [128][32] with an
// XOR-4 chunk swizzle (8-way -> 4-way ds_read_b128 bank conflicts).
// Store: cols < stn into C (row stride ldc).
// ---------------------------------------------------------------------------
template<bool OUT_BF16>
__global__ __launch_bounds__(256) void gemm_mfma_gll(
    const unsigned short* __restrict__ A, int lda,
    const unsigned short* __restrict__ Bw, int ldb,
    const float* __restrict__ bias,
    void* __restrict__ Cp, int ldc, int stn,
    int K)
{
    constexpr int BM = 128, BN = 128, BK = 32;
    __shared__ __align__(16) unsigned short As[BM][BK];  // 8 KB, unpadded (gll)
    __shared__ __align__(16) unsigned short Bs[BN][BK];  // 8 KB

    const int tid  = threadIdx.x;
    const int wave = tid >> 6;
    const int lane = tid & 63;
    const int quad = lane >> 4;
    const int l16  = lane & 15;
    const int wm = (wave & 1) * 64;
    const int wn = (wave >> 1) * 64;
    const int m0 = blockIdx.x * BM;
    const int n0 = blockIdx.y * BN;

    // gll staging geometry: segment = wave*2+p (0..7), 1024 B each (16 rows).
    // lane -> row r = seg*16 + lane/4, chunk slot = lane&3, global chunk
    // c = (lane&3) ^ (r&3)  [XOR swizzle].
    const int sr   = lane >> 2;                 // 0..15 within segment
    const int slot = lane & 3;

    float4v acc[4][4];
    #pragma unroll
    for (int i = 0; i < 4; ++i)
        #pragma unroll
        for (int j = 0; j < 4; ++j)
            acc[i][j] = (float4v)(0.f);

    // fragment LDS chunk slot (uniform per lane): quad ^ (row&3), row&3 == l16&3
    const int fslot = (quad ^ (l16 & 3)) * 8;

    for (int k0 = 0; k0 < K; k0 += BK) {
        #pragma unroll
        for (int p = 0; p < 2; ++p) {
            const int seg = wave * 2 + p;
            const int r   = seg * 16 + sr;
            const int c   = slot ^ (r & 3);
            const unsigned short* gA = A + (size_t)(m0 + r) * lda + k0 + c * 8;
            unsigned short* lA = &As[0][0] + seg * 512 + lane * 8;
            __builtin_amdgcn_global_load_lds(
                (const __attribute__((address_space(1))) unsigned int*)gA,
                (__attribute__((address_space(3))) unsigned int*)lA, 16, 0, 0);
            const unsigned short* gB = Bw + (size_t)(n0 + r) * ldb + k0 + c * 8;
            unsigned short* lB = &Bs[0][0] + seg * 512 + lane * 8;
            __builtin_amdgcn_global_load_lds(
                (const __attribute__((address_space(1))) unsigned int*)gB,
                (__attribute__((address_space(3))) unsigned int*)lB, 16, 0, 0);
        }
        __syncthreads();  // drains vmcnt (gll) for all waves

        short8 af[4], bf[4];
        #pragma unroll
        for (int i = 0; i < 4; ++i)
            af[i] = *(const short8*)(&As[wm + i * 16 + l16][fslot]);
        #pragma unroll
        for (int j = 0; j < 4; ++j)
            bf[j] = *(const short8*)(&Bs[wn + j * 16 + l16][fslot]);

        #pragma unroll
        for (int i = 0; i < 4; ++i)
            #pragma unroll
            for (int j = 0; j < 4; ++j)
                acc[i][j] = __builtin_amdgcn_mfma_f32_16x16x32_bf16(
                    af[i], bf[j], acc[i][j], 0, 0, 0);
        __syncthreads();
    }

    #pragma unroll
    for (int i = 0; i < 4; ++i) {
        const int rbase = m0 + wm + i * 16 + quad * 4;
        #pragma unroll
        for (int j = 0; j < 4; ++j) {
            const int col = n0 + wn + j * 16 + l16;
            if (col < stn) {
                const float bv = bias[col];
                #pragma unroll
                for (int r2 = 0; r2 < 4; ++r2) {
                    float v = acc[i][j][r2] + bv;
                    v = v > 0.f ? v : 0.f;
                    if (OUT_BF16)
                        ((unsigned short*)Cp)[(size_t)(rbase + r2) * ldc + col] = f2bf(v);
                    else
                        ((float*)Cp)[(size_t)(rbase + r2) * ldc + col] = v;
                }
            }
        }
    }
}

// ---------------------------------------------------------------------------
// Final dot over the 471-wide concat. One wave per row.
// ---------------------------------------------------------------------------
__global__ __launch_bounds__(256) void final_kernel(
    const float* __restrict__ fo,
    const float* __restrict__ so,
    const float* __restrict__ dy,
    const float* __restrict__ fW,
    const float* __restrict__ fb,
    float* __restrict__ out)
{
    const int lane = threadIdx.x & 63;
    const int wave = threadIdx.x >> 6;
    const int r = blockIdx.x * 4 + wave;

    float s = 0.f;
    if (lane < FIELD)
        s += fo[(size_t)r * FIELD + lane] * fW[lane];
    if (lane < EMB)
        s += so[(size_t)r * EMB + lane] * fW[FIELD + lane];
    for (int e = lane; e < HID; e += 64)
        s += dy[(size_t)r * HID + e] * fW[FIELD + EMB + e];

    #pragma unroll
    for (int off = 32; off > 0; off >>= 1)
        s += __shfl_down(s, off, 64);

    if (lane == 0)
        out[r] = s + fb[0];
}

// ---------------------------------------------------------------------------
extern "C" void kernel_launch(void* const* d_in, const int* in_sizes, int n_in,
                              void* d_out, int out_size, void* d_ws, size_t ws_size,
                              hipStream_t stream)
{
    const int*   feat_index = (const int*)d_in[0];
    const float* feat_value = (const float*)d_in[1];
    const float* emb_table  = (const float*)d_in[2];
    const float* bias_table = (const float*)d_in[3];
    const float* W1         = (const float*)d_in[4];
    const float* b1         = (const float*)d_in[5];
    const float* W2         = (const float*)d_in[6];
    const float* b2         = (const float*)d_in[7];
    const float* fW         = (const float*)d_in[8];
    const float* fb         = (const float*)d_in[9];

    float* out = (float*)d_out;
    float* out0 = out;
    float* fo   = out + BATCH;
    float* so   = out + (size_t)BATCH * (1 + FIELD);
    float* dy   = out + (size_t)BATCH * (1 + FIELD + EMB);

    // workspace layout (bf16 counts; all 16B-aligned):
    unsigned short* emb_ws = (unsigned short*)d_ws;                 // B x 1248
    unsigned short* h1     = emb_ws + (size_t)BATCH * DIN;          // B x 416
    unsigned short* W1b    = h1 + (size_t)BATCH * K2P;              // 512 x 1248
    unsigned short* W2b    = W1b + (size_t)NPAD * DIN;              // 512 x 416
    float*          b1p    = (float*)(W2b + (size_t)NPAD * K2P);    // 512
    float*          b2p    = b1p + NPAD;                            // 512

    const int ncvt = NPAD * DIN + NPAD * K2P + 2 * NPAD;
    cvt_weights<<<(ncvt + 255) / 256, 256, 0, stream>>>(
        W1, W2, b1, b2, W1b, W2b, b1p, b2p);

    gather_fm_kernel<<<BATCH / 4, 256, 0, stream>>>(
        feat_index, feat_value, emb_table, bias_table, emb_ws, fo, so);

    dim3 grid_g(BATCH / 128, NPAD / 128);  // 128 x 4
    // GEMM1: h1 = relu(emb @ W1^T + b1), stored bf16 with K2P stride
    //        (cols 400..415 get relu(0+0)=0 -> the K2 zero-padding for GEMM2)
    gemm_mfma_gll<true ><<<grid_g, 256, 0, stream>>>(
        emb_ws, DIN, W1b, DIN, b1p, h1, K2P, K2P, DIN);
    // GEMM2: dy = relu(h1 @ W2^T + b2), fp32 into d_out
    gemm_mfma_gll<false><<<grid_g, 256, 0, stream>>>(
        h1, K2P, W2b, K2P, b2p, dy, HID, HID, K2P);

    final_kernel<<<BATCH / 4, 256, 0, stream>>>(fo, so, dy, fW, fb, out0);
}

// Round 4
// 267.271 us; speedup vs baseline: 2.2294x; 1.0408x over previous
//
#include <hip/hip_runtime.h>
#include <hip/hip_bf16.h>

// DeepFM constants
#define BATCH 16384
#define FIELD 39
#define EMB 32
#define DIN 1248               // FIELD*EMB
#define K1P 1280               // padded K for GEMM1 (20*64)
#define HID 400
#define K2P 448                // padded K for GEMM2 (7*64)
#define NPAD 512               // padded N for both GEMMs

typedef __attribute__((ext_vector_type(8))) short short8;   // 8 bf16 = 4 VGPRs
typedef __attribute__((ext_vector_type(4))) float float4v;  // MFMA C/D

static __device__ __forceinline__ unsigned short f2bf(float f) {
    __hip_bfloat16 h = __float2bfloat16(f);  // RNE
    return *(unsigned short*)&h;
}

// ---------------------------------------------------------------------------
// Kernel 1 (prep): block-range-split combo.
//   blocks [0, 4096): wave-per-row gather: emb (bf16, stride K1P, zero-padded),
//     first_order, second_order, AND out0[r] = fb + fo.fW + so.fW
//     (each wave owns row r exclusively -> plain store, no init kernel needed).
//   blocks [4096, ...): weight cvt fp32->bf16 with zero padding:
//     W1b: NPAD x K1P, W2b: NPAD x K2P, b1p/b2p: NPAD.
// ---------------------------------------------------------------------------
#define CVT_ELEMS (NPAD * K1P + NPAD * K2P + 2 * NPAD)   // 886272 = 3462*256
#define GATHER_BLOCKS (BATCH / 4)

__global__ __launch_bounds__(256) void prep_kernel(
    const int* __restrict__ feat_index,
    const float* __restrict__ feat_value,
    const float* __restrict__ emb_table,
    const float* __restrict__ bias_table,
    const float* __restrict__ W1, const float* __restrict__ b1,
    const float* __restrict__ W2, const float* __restrict__ b2,
    const float* __restrict__ fW, const float* __restrict__ fb,
    unsigned short* __restrict__ emb_ws,   // BATCH x K1P (bf16)
    unsigned short* __restrict__ W1b,      // NPAD x K1P
    unsigned short* __restrict__ W2b,      // NPAD x K2P
    float* __restrict__ b1p, float* __restrict__ b2p,
    float* __restrict__ first_order,       // BATCH x FIELD
    float* __restrict__ second_order,      // BATCH x EMB
    float* __restrict__ out0)              // BATCH
{
    if (blockIdx.x < GATHER_BLOCKS) {
        const int lane = threadIdx.x & 63;
        const int wave = threadIdx.x >> 6;
        const int r = blockIdx.x * 4 + wave;

        int   idx0 = 0;
        float val0 = 0.f;
        float s1 = 0.f;   // fo . fW contribution (per lane)
        if (lane < FIELD) {
            idx0 = feat_index[r * FIELD + lane];
            val0 = feat_value[r * FIELD + lane];
            float fov = bias_table[idx0] * val0;
            first_order[r * FIELD + lane] = fov;
            s1 = fov * fW[lane];
        }

        const int fsub = lane >> 3;       // 0..7
        const int j4   = (lane & 7) * 4;  // dim quad offset

        float sx = 0.f, sy = 0.f, sz = 0.f, sw = 0.f;
        float qx = 0.f, qy = 0.f, qz = 0.f, qw = 0.f;

        #pragma unroll
        for (int step = 0; step < 5; ++step) {
            const int   f  = step * 8 + fsub;        // 0..39
            const int   fi = __shfl(idx0, f, 64);
            const float fv = __shfl(val0, f, 64);
            float4 e4 = make_float4(0.f, 0.f, 0.f, 0.f);
            if (f < FIELD) {
                float4 t = *(const float4*)(emb_table + (size_t)fi * EMB + j4);
                e4.x = t.x * fv; e4.y = t.y * fv; e4.z = t.z * fv; e4.w = t.w * fv;
                uint2 pk;
                pk.x = (unsigned)f2bf(e4.x) | ((unsigned)f2bf(e4.y) << 16);
                pk.y = (unsigned)f2bf(e4.z) | ((unsigned)f2bf(e4.w) << 16);
                *(uint2*)(emb_ws + (size_t)r * K1P + step * 256 + lane * 4) = pk;
            }
            sx += e4.x; sy += e4.y; sz += e4.z; sw += e4.w;
            qx += e4.x * e4.x; qy += e4.y * e4.y; qz += e4.z * e4.z; qw += e4.w * e4.w;
        }

        // zero-pad emb cols 1248..1279 (K1P guard-free GEMM1)
        if (lane < 8) {
            uint2 z; z.x = 0u; z.y = 0u;
            *(uint2*)(emb_ws + (size_t)r * K1P + DIN + lane * 4) = z;
        }

        #pragma unroll
        for (int d = 8; d < 64; d <<= 1) {
            sx += __shfl_xor(sx, d, 64); sy += __shfl_xor(sy, d, 64);
            sz += __shfl_xor(sz, d, 64); sw += __shfl_xor(sw, d, 64);
            qx += __shfl_xor(qx, d, 64); qy += __shfl_xor(qy, d, 64);
            qz += __shfl_xor(qz, d, 64); qw += __shfl_xor(qw, d, 64);
        }

        float s2 = 0.f;   // so . fW contribution (lanes 0..7)
        if (lane < 8) {
            float4 so4;
            so4.x = 0.5f * (sx * sx - qx);
            so4.y = 0.5f * (sy * sy - qy);
            so4.z = 0.5f * (sz * sz - qz);
            so4.w = 0.5f * (sw * sw - qw);
            *(float4*)(second_order + (size_t)r * EMB + lane * 4) = so4;
            const float* fw = fW + FIELD + lane * 4;
            s2 = so4.x * fw[0] + so4.y * fw[1] + so4.z * fw[2] + so4.w * fw[3];
        }

        float s = s1 + s2;
        #pragma unroll
        for (int d = 1; d < 64; d <<= 1)
            s += __shfl_xor(s, d, 64);
        if (lane == 0)
            out0[r] = s + fb[0];
    } else {
        int i = (blockIdx.x - GATHER_BLOCKS) * 256 + threadIdx.x;
        const int n1p = NPAD * K1P;
        const int n2p = NPAD * K2P;
        if (i < n1p) {
            int row = i / K1P, col = i - row * K1P;
            W1b[i] = (row < HID && col < DIN)
                   ? f2bf(W1[row * DIN + col]) : (unsigned short)0;
        } else if (i < n1p + n2p) {
            int j = i - n1p;
            int row = j / K2P, col = j - row * K2P;
            W2b[j] = (row < HID && col < HID)
                   ? f2bf(W2[row * HID + col]) : (unsigned short)0;
        } else if (i < n1p + n2p + NPAD) {
            int k = i - n1p - n2p;
            b1p[k] = (k < HID) ? b1[k] : 0.f;
        } else if (i < n1p + n2p + 2 * NPAD) {
            int k = i - n1p - n2p - NPAD;
            b2p[k] = (k < HID) ? b2[k] : 0.f;
        }
    }
}

// ---------------------------------------------------------------------------
// MFMA NT-GEMM, BK=64, m97-pattern gll staging, XOR-8 chunk swizzle
// (fragment ds_read_b128 at minimum 2-lane/bank aliasing = conflict-free).
// C = relu(A * Bw^T + bias); A: M x K (stride lda), Bw: NPAD x K (padded,
// guard-free), K multiple of 64. Stores cols < stn at stride ldc.
// FINAL_DOT: also atomicAdd per-row partial of C-row . fW[71+col] into out0.
// ---------------------------------------------------------------------------
template<bool OUT_BF16, bool FINAL_DOT>
__global__ __launch_bounds__(256) void gemm_mfma(
    const unsigned short* __restrict__ A, int lda,
    const unsigned short* __restrict__ Bw, int ldb,
    const float* __restrict__ bias,
    void* __restrict__ Cp, int ldc, int stn, int K,
    const float* __restrict__ fW, float* __restrict__ out0)
{
    constexpr int BM = 128, BN = 128, BK = 64;
    __shared__ __align__(16) unsigned short As[BM * BK];  // 16 KB
    __shared__ __align__(16) unsigned short Bs[BN * BK];  // 16 KB
    __shared__ float part[2][BM];                          // 1 KB (FINAL_DOT)

    const int tid  = threadIdx.x;
    const int wave = tid >> 6;
    const int lane = tid & 63;
    const int quad = lane >> 4;
    const int l16  = lane & 15;
    const int wm = (wave & 1) * 64;
    const int wn = (wave >> 1) * 64;
    const int m0 = blockIdx.x * BM;
    const int n0 = blockIdx.y * BN;

    // gll staging: 16 segments/side of 1 KB (8 rows x 128 B). Lane lam:
    // row-in-seg = lam>>3, slot = lam&7, global chunk = slot ^ (row&7).
    const int lrow8 = lane >> 3;                 // 0..7
    const int cg    = (lane & 7) ^ lrow8;        // swizzled global chunk

    float4v acc[4][4];
    #pragma unroll
    for (int i = 0; i < 4; ++i)
        #pragma unroll
        for (int j = 0; j < 4; ++j)
            acc[i][j] = (float4v)(0.f);

    for (int k0 = 0; k0 < K; k0 += BK) {
        #pragma unroll
        for (int p = 0; p < 4; ++p) {
            const int seg = wave * 4 + p;        // 0..15
            const int r   = seg * 8 + lrow8;
            const unsigned short* gA = A + (size_t)(m0 + r) * lda + k0 + cg * 8;
            unsigned short* lA = As + seg * 512 + lane * 8;
            __builtin_amdgcn_global_load_lds(
                (const __attribute__((address_space(1))) unsigned int*)gA,
                (__attribute__((address_space(3))) unsigned int*)lA, 16, 0, 0);
            const unsigned short* gB = Bw + (size_t)(n0 + r) * ldb + k0 + cg * 8;
            unsigned short* lB = Bs + seg * 512 + lane * 8;
            __builtin_amdgcn_global_load_lds(
                (const __attribute__((address_space(1))) unsigned int*)gB,
                (__attribute__((address_space(3))) unsigned int*)lB, 16, 0, 0);
        }
        __syncthreads();

        #pragma unroll
        for (int s = 0; s < 2; ++s) {
            short8 af[4], bf[4];
            #pragma unroll
            for (int i = 0; i < 4; ++i)
                af[i] = *(const short8*)(As + (wm + i * 16 + l16) * 64
                                            + (((s * 4 + quad) ^ (l16 & 7)) * 8));
            #pragma unroll
            for (int j = 0; j < 4; ++j)
                bf[j] = *(const short8*)(Bs + (wn + j * 16 + l16) * 64
                                            + (((s * 4 + quad) ^ (l16 & 7)) * 8));
            #pragma unroll
            for (int i = 0; i < 4; ++i)
                #pragma unroll
                for (int j = 0; j < 4; ++j)
                    acc[i][j] = __builtin_amdgcn_mfma_f32_16x16x32_bf16(
                        af[i], bf[j], acc[i][j], 0, 0, 0);
        }
        __syncthreads();
    }

    // epilogue: bias + relu + store (cols < stn)
    #pragma unroll
    for (int i = 0; i < 4; ++i) {
        const int rbase = m0 + wm + i * 16 + quad * 4;
        #pragma unroll
        for (int j = 0; j < 4; ++j) {
            const int col = n0 + wn + j * 16 + l16;
            if (col < stn) {
                const float bv = bias[col];
                #pragma unroll
                for (int r2 = 0; r2 < 4; ++r2) {
                    float v = acc[i][j][r2] + bv;
                    v = v > 0.f ? v : 0.f;
                    acc[i][j][r2] = v;
                    if (OUT_BF16)
                        ((unsigned short*)Cp)[(size_t)(rbase + r2) * ldc + col] = f2bf(v);
                    else
                        ((float*)Cp)[(size_t)(rbase + r2) * ldc + col] = v;
                }
            } else {
                #pragma unroll
                for (int r2 = 0; r2 < 4; ++r2) acc[i][j][r2] = 0.f;
            }
        }
    }

    if (FINAL_DOT) {
        // per-row partial dot with fW[71+col] from registers
        #pragma unroll
        for (int i = 0; i < 4; ++i) {
            #pragma unroll
            for (int r2 = 0; r2 < 4; ++r2) {
                float s = 0.f;
                #pragma unroll
                for (int j = 0; j < 4; ++j) {
                    const int col = n0 + wn + j * 16 + l16;
                    const float fwv = (col < HID) ? fW[FIELD + EMB + col] : 0.f;
                    s = fmaf(acc[i][j][r2], fwv, s);
                }
                s += __shfl_xor(s, 1, 64); s += __shfl_xor(s, 2, 64);
                s += __shfl_xor(s, 4, 64); s += __shfl_xor(s, 8, 64);
                if (l16 == 0)
                    part[wn >> 6][wm + i * 16 + quad * 4 + r2] = s;
            }
        }
        __syncthreads();
        if (tid < BM)
            atomicAdd(out0 + m0 + tid, part[0][tid] + part[1][tid]);
    }
}

// ---------------------------------------------------------------------------
extern "C" void kernel_launch(void* const* d_in, const int* in_sizes, int n_in,
                              void* d_out, int out_size, void* d_ws, size_t ws_size,
                              hipStream_t stream)
{
    const int*   feat_index = (const int*)d_in[0];
    const float* feat_value = (const float*)d_in[1];
    const float* emb_table  = (const float*)d_in[2];
    const float* bias_table = (const float*)d_in[3];
    const float* W1         = (const float*)d_in[4];
    const float* b1         = (const float*)d_in[5];
    const float* W2         = (const float*)d_in[6];
    const float* b2         = (const float*)d_in[7];
    const float* fW         = (const float*)d_in[8];
    const float* fb         = (const float*)d_in[9];

    float* out = (float*)d_out;
    float* out0 = out;
    float* fo   = out + BATCH;
    float* so   = out + (size_t)BATCH * (1 + FIELD);
    float* dy   = out + (size_t)BATCH * (1 + FIELD + EMB);

    // workspace layout (bf16 element counts; all 16B-aligned):
    unsigned short* emb_ws = (unsigned short*)d_ws;                 // B x 1280
    unsigned short* h1     = emb_ws + (size_t)BATCH * K1P;          // B x 448
    unsigned short* W1b    = h1 + (size_t)BATCH * K2P;              // 512 x 1280
    unsigned short* W2b    = W1b + (size_t)NPAD * K1P;              // 512 x 448
    float*          b1p    = (float*)(W2b + (size_t)NPAD * K2P);    // 512
    float*          b2p    = b1p + NPAD;                            // 512

    const int cvt_blocks = (CVT_ELEMS + 255) / 256;  // 3462
    prep_kernel<<<GATHER_BLOCKS + cvt_blocks, 256, 0, stream>>>(
        feat_index, feat_value, emb_table, bias_table,
        W1, b1, W2, b2, fW, fb,
        emb_ws, W1b, W2b, b1p, b2p, fo, so, out0);

    dim3 grid_g(BATCH / 128, NPAD / 128);  // 128 x 4
    // GEMM1: h1 = relu(emb @ W1^T + b1) -> bf16, stride/store K2P (cols
    // 400..447 come out exactly 0 -> K2 zero padding for GEMM2)
    gemm_mfma<true, false><<<grid_g, 256, 0, stream>>>(
        emb_ws, K1P, W1b, K1P, b1p, h1, K2P, K2P, K1P, nullptr, nullptr);
    // GEMM2: dy = relu(h1 @ W2^T + b2) -> fp32 + fused final-dot atomics
    gemm_mfma<false, true><<<grid_g, 256, 0, stream>>>(
        h1, K2P, W2b, K2P, b2p, dy, HID, HID, K2P, fW, out0);
}

// Round 5
// 264.036 us; speedup vs baseline: 2.2567x; 1.0123x over previous
//
#include <hip/hip_runtime.h>
#include <hip/hip_bf16.h>

// DeepFM constants
#define BATCH 16384
#define FIELD 39
#define EMB 32
#define DIN 1248               // FIELD*EMB
#define K1P 1280               // padded K for GEMM1 (10*128)
#define HID 400
#define K2P 448                // padded K for GEMM2 (7*64)
#define NPAD 512               // padded N for both GEMMs

typedef __attribute__((ext_vector_type(8))) short short8;   // 8 bf16 = 4 VGPRs
typedef __attribute__((ext_vector_type(4))) float float4v;  // MFMA C/D

static __device__ __forceinline__ unsigned short f2bf(float f) {
    __hip_bfloat16 h = __float2bfloat16(f);  // RNE
    return *(unsigned short*)&h;
}

// ---------------------------------------------------------------------------
// Kernel 1 (prep): block-range-split combo.
//   blocks [0, 4096): wave-per-row gather: emb (bf16, stride K1P, zero-padded),
//     first_order, second_order, AND out0[r] = fb + fo.fW + so.fW.
//   blocks [4096, ...): weight cvt fp32->bf16 with zero padding.
// ---------------------------------------------------------------------------
#define CVT_ELEMS (NPAD * K1P + NPAD * K2P + 2 * NPAD)
#define GATHER_BLOCKS (BATCH / 4)

__global__ __launch_bounds__(256) void prep_kernel(
    const int* __restrict__ feat_index,
    const float* __restrict__ feat_value,
    const float* __restrict__ emb_table,
    const float* __restrict__ bias_table,
    const float* __restrict__ W1, const float* __restrict__ b1,
    const float* __restrict__ W2, const float* __restrict__ b2,
    const float* __restrict__ fW, const float* __restrict__ fb,
    unsigned short* __restrict__ emb_ws,   // BATCH x K1P (bf16)
    unsigned short* __restrict__ W1b,      // NPAD x K1P
    unsigned short* __restrict__ W2b,      // NPAD x K2P
    float* __restrict__ b1p, float* __restrict__ b2p,
    float* __restrict__ first_order,       // BATCH x FIELD
    float* __restrict__ second_order,      // BATCH x EMB
    float* __restrict__ out0)              // BATCH
{
    if (blockIdx.x < GATHER_BLOCKS) {
        const int lane = threadIdx.x & 63;
        const int wave = threadIdx.x >> 6;
        const int r = blockIdx.x * 4 + wave;

        int   idx0 = 0;
        float val0 = 0.f;
        float s1 = 0.f;
        if (lane < FIELD) {
            idx0 = feat_index[r * FIELD + lane];
            val0 = feat_value[r * FIELD + lane];
            float fov = bias_table[idx0] * val0;
            first_order[r * FIELD + lane] = fov;
            s1 = fov * fW[lane];
        }

        const int fsub = lane >> 3;
        const int j4   = (lane & 7) * 4;

        float sx = 0.f, sy = 0.f, sz = 0.f, sw = 0.f;
        float qx = 0.f, qy = 0.f, qz = 0.f, qw = 0.f;

        #pragma unroll
        for (int step = 0; step < 5; ++step) {
            const int   f  = step * 8 + fsub;
            const int   fi = __shfl(idx0, f, 64);
            const float fv = __shfl(val0, f, 64);
            float4 e4 = make_float4(0.f, 0.f, 0.f, 0.f);
            if (f < FIELD) {
                float4 t = *(const float4*)(emb_table + (size_t)fi * EMB + j4);
                e4.x = t.x * fv; e4.y = t.y * fv; e4.z = t.z * fv; e4.w = t.w * fv;
                uint2 pk;
                pk.x = (unsigned)f2bf(e4.x) | ((unsigned)f2bf(e4.y) << 16);
                pk.y = (unsigned)f2bf(e4.z) | ((unsigned)f2bf(e4.w) << 16);
                *(uint2*)(emb_ws + (size_t)r * K1P + step * 256 + lane * 4) = pk;
            }
            sx += e4.x; sy += e4.y; sz += e4.z; sw += e4.w;
            qx += e4.x * e4.x; qy += e4.y * e4.y; qz += e4.z * e4.z; qw += e4.w * e4.w;
        }

        if (lane < 8) {
            uint2 z; z.x = 0u; z.y = 0u;
            *(uint2*)(emb_ws + (size_t)r * K1P + DIN + lane * 4) = z;
        }

        #pragma unroll
        for (int d = 8; d < 64; d <<= 1) {
            sx += __shfl_xor(sx, d, 64); sy += __shfl_xor(sy, d, 64);
            sz += __shfl_xor(sz, d, 64); sw += __shfl_xor(sw, d, 64);
            qx += __shfl_xor(qx, d, 64); qy += __shfl_xor(qy, d, 64);
            qz += __shfl_xor(qz, d, 64); qw += __shfl_xor(qw, d, 64);
        }

        float s2 = 0.f;
        if (lane < 8) {
            float4 so4;
            so4.x = 0.5f * (sx * sx - qx);
            so4.y = 0.5f * (sy * sy - qy);
            so4.z = 0.5f * (sz * sz - qz);
            so4.w = 0.5f * (sw * sw - qw);
            *(float4*)(second_order + (size_t)r * EMB + lane * 4) = so4;
            const float* fw = fW + FIELD + lane * 4;
            s2 = so4.x * fw[0] + so4.y * fw[1] + so4.z * fw[2] + so4.w * fw[3];
        }

        float s = s1 + s2;
        #pragma unroll
        for (int d = 1; d < 64; d <<= 1)
            s += __shfl_xor(s, d, 64);
        if (lane == 0)
            out0[r] = s + fb[0];
    } else {
        int i = (blockIdx.x - GATHER_BLOCKS) * 256 + threadIdx.x;
        const int n1p = NPAD * K1P;
        const int n2p = NPAD * K2P;
        if (i < n1p) {
            int row = i / K1P, col = i - row * K1P;
            W1b[i] = (row < HID && col < DIN)
                   ? f2bf(W1[row * DIN + col]) : (unsigned short)0;
        } else if (i < n1p + n2p) {
            int j = i - n1p;
            int row = j / K2P, col = j - row * K2P;
            W2b[j] = (row < HID && col < HID)
                   ? f2bf(W2[row * HID + col]) : (unsigned short)0;
        } else if (i < n1p + n2p + NPAD) {
            int k = i - n1p - n2p;
            b1p[k] = (k < HID) ? b1[k] : 0.f;
        } else if (i < n1p + n2p + 2 * NPAD) {
            int k = i - n1p - n2p - NPAD;
            b2p[k] = (k < HID) ? b2[k] : 0.f;
        }
    }
}

// ---------------------------------------------------------------------------
// MFMA NT-GEMM, templated BK (128 for GEMM1, 64 for GEMM2), m97-pattern gll
// staging, XOR chunk swizzle (fragment ds_read_b128 at 2-lane/bank = free).
// C = relu(A * Bw^T + bias); Bw is NPAD x K padded/guard-free; K % BK == 0.
// Stores cols < stn at stride ldc. Dead-wave skip: waves whose 64-col span
// lies entirely >= stn skip B-staging, fragment reads, and MFMAs.
// FINAL_DOT: atomicAdd per-row partial of C-row . fW[71+col] into out0.
// ---------------------------------------------------------------------------
template<int BK, bool OUT_BF16, bool FINAL_DOT>
__global__ __launch_bounds__(256) void gemm_mfma(
    const unsigned short* __restrict__ A, int lda,
    const unsigned short* __restrict__ Bw, int ldb,
    const float* __restrict__ bias,
    void* __restrict__ Cp, int ldc, int stn, int K,
    const float* __restrict__ fW, float* __restrict__ out0)
{
    constexpr int BM = 128, BN = 128;
    constexpr int CH  = BK / 8;            // 16B chunks per LDS row
    constexpr int RPS = 512 / BK;          // rows per 1KB gll segment
    constexpr int PASSES = BM * BK / 2048; // gll passes per side
    __shared__ __align__(16) unsigned short As[BM * BK];
    __shared__ __align__(16) unsigned short Bs[BN * BK];
    __shared__ float part[2][BM];

    const int tid  = threadIdx.x;
    const int wave = tid >> 6;
    const int lane = tid & 63;
    const int quad = lane >> 4;
    const int l16  = lane & 15;
    const int wm = (wave & 1) * 64;
    const int wn = (wave >> 1) * 64;
    const int m0 = blockIdx.x * BM;
    const int n0 = blockIdx.y * BN;

    // staging geometry: 1KB segments, CH lanes per row, XOR chunk swizzle
    const int lr   = lane / CH;            // row within segment
    const int slot = lane % CH;            // physical 16B chunk slot

    // dead waves: whole 64-col span >= stn (only possible in last n-tile)
    const bool waveDead = (wave >= 2) && (n0 + 64 >= stn);

    float4v acc[4][4];
    #pragma unroll
    for (int i = 0; i < 4; ++i)
        #pragma unroll
        for (int j = 0; j < 4; ++j)
            acc[i][j] = (float4v)(0.f);

    for (int k0 = 0; k0 < K; k0 += BK) {
        #pragma unroll
        for (int p = 0; p < PASSES; ++p) {
            const int seg = wave * PASSES + p;
            const int r   = seg * RPS + lr;
            const int c   = slot ^ (r & (CH - 1));
            const unsigned short* gA = A + (size_t)(m0 + r) * lda + k0 + c * 8;
            unsigned short* lA = As + seg * 512 + lane * 8;
            __builtin_amdgcn_global_load_lds(
                (const __attribute__((address_space(1))) unsigned int*)gA,
                (__attribute__((address_space(3))) unsigned int*)lA, 16, 0, 0);
            if (!waveDead) {   // B rows 64..127 are only read by waves 2,3
                const unsigned short* gB = Bw + (size_t)(n0 + r) * ldb + k0 + c * 8;
                unsigned short* lB = Bs + seg * 512 + lane * 8;
                __builtin_amdgcn_global_load_lds(
                    (const __attribute__((address_space(1))) unsigned int*)gB,
                    (__attribute__((address_space(3))) unsigned int*)lB, 16, 0, 0);
            }
        }
        __syncthreads();

        if (!waveDead) {
            #pragma unroll
            for (int s = 0; s < BK / 32; ++s) {
                short8 af[4], bf[4];
                #pragma unroll
                for (int i = 0; i < 4; ++i)
                    af[i] = *(const short8*)(As + (wm + i * 16 + l16) * BK
                                            + (((s * 4 + quad) ^ (l16 & (CH - 1))) * 8));
                #pragma unroll
                for (int j = 0; j < 4; ++j)
                    bf[j] = *(const short8*)(Bs + (wn + j * 16 + l16) * BK
                                            + (((s * 4 + quad) ^ (l16 & (CH - 1))) * 8));
                #pragma unroll
                for (int i = 0; i < 4; ++i)
                    #pragma unroll
                    for (int j = 0; j < 4; ++j)
                        acc[i][j] = __builtin_amdgcn_mfma_f32_16x16x32_bf16(
                            af[i], bf[j], acc[i][j], 0, 0, 0);
            }
        }
        __syncthreads();
    }

    // epilogue: bias + relu + store (cols < stn)
    #pragma unroll
    for (int i = 0; i < 4; ++i) {
        const int rbase = m0 + wm + i * 16 + quad * 4;
        #pragma unroll
        for (int j = 0; j < 4; ++j) {
            const int col = n0 + wn + j * 16 + l16;
            if (col < stn) {
                const float bv = bias[col];
                #pragma unroll
                for (int r2 = 0; r2 < 4; ++r2) {
                    float v = acc[i][j][r2] + bv;
                    v = v > 0.f ? v : 0.f;
                    acc[i][j][r2] = v;
                    if (OUT_BF16)
                        ((unsigned short*)Cp)[(size_t)(rbase + r2) * ldc + col] = f2bf(v);
                    else  // dy is never re-read on device: nontemporal
                        __builtin_nontemporal_store(
                            v, ((float*)Cp) + (size_t)(rbase + r2) * ldc + col);
                }
            } else {
                #pragma unroll
                for (int r2 = 0; r2 < 4; ++r2) acc[i][j][r2] = 0.f;
            }
        }
    }

    if (FINAL_DOT) {
        #pragma unroll
        for (int i = 0; i < 4; ++i) {
            #pragma unroll
            for (int r2 = 0; r2 < 4; ++r2) {
                float s = 0.f;
                #pragma unroll
                for (int j = 0; j < 4; ++j) {
                    const int col = n0 + wn + j * 16 + l16;
                    const float fwv = (col < HID) ? fW[FIELD + EMB + col] : 0.f;
                    s = fmaf(acc[i][j][r2], fwv, s);
                }
                s += __shfl_xor(s, 1, 64); s += __shfl_xor(s, 2, 64);
                s += __shfl_xor(s, 4, 64); s += __shfl_xor(s, 8, 64);
                if (l16 == 0)
                    part[wn >> 6][wm + i * 16 + quad * 4 + r2] = s;
            }
        }
        __syncthreads();
        if (tid < BM)
            atomicAdd(out0 + m0 + tid, part[0][tid] + part[1][tid]);
    }
}

// ---------------------------------------------------------------------------
extern "C" void kernel_launch(void* const* d_in, const int* in_sizes, int n_in,
                              void* d_out, int out_size, void* d_ws, size_t ws_size,
                              hipStream_t stream)
{
    const int*   feat_index = (const int*)d_in[0];
    const float* feat_value = (const float*)d_in[1];
    const float* emb_table  = (const float*)d_in[2];
    const float* bias_table = (const float*)d_in[3];
    const float* W1         = (const float*)d_in[4];
    const float* b1         = (const float*)d_in[5];
    const float* W2         = (const float*)d_in[6];
    const float* b2         = (const float*)d_in[7];
    const float* fW         = (const float*)d_in[8];
    const float* fb         = (const float*)d_in[9];

    float* out = (float*)d_out;
    float* out0 = out;
    float* fo   = out + BATCH;
    float* so   = out + (size_t)BATCH * (1 + FIELD);
    float* dy   = out + (size_t)BATCH * (1 + FIELD + EMB);

    // workspace layout (bf16 element counts; all 16B-aligned):
    unsigned short* emb_ws = (unsigned short*)d_ws;                 // B x 1280
    unsigned short* h1     = emb_ws + (size_t)BATCH * K1P;          // B x 448
    unsigned short* W1b    = h1 + (size_t)BATCH * K2P;              // 512 x 1280
    unsigned short* W2b    = W1b + (size_t)NPAD * K1P;              // 512 x 448
    float*          b1p    = (float*)(W2b + (size_t)NPAD * K2P);    // 512
    float*          b2p    = b1p + NPAD;                            // 512

    const int cvt_blocks = (CVT_ELEMS + 255) / 256;
    prep_kernel<<<GATHER_BLOCKS + cvt_blocks, 256, 0, stream>>>(
        feat_index, feat_value, emb_table, bias_table,
        W1, b1, W2, b2, fW, fb,
        emb_ws, W1b, W2b, b1p, b2p, fo, so, out0);

    dim3 grid_g(BATCH / 128, NPAD / 128);  // 128 x 4
    // GEMM1: h1 = relu(emb @ W1^T + b1) -> bf16 at stride K2P; cols 400..447
    // come out exactly 0 (zero-padded weights/bias) = K2 padding for GEMM2.
    // stn=448 so only the cols-448..511 waves are dead-skipped.
    gemm_mfma<128, true, false><<<grid_g, 256, 0, stream>>>(
        emb_ws, K1P, W1b, K1P, b1p, h1, K2P, K2P, K1P, nullptr, nullptr);
    // GEMM2: dy = relu(h1 @ W2^T + b2) -> fp32 (nontemporal) + fused final dot
    gemm_mfma<64, false, true><<<grid_g, 256, 0, stream>>>(
        h1, K2P, W2b, K2P, b2p, dy, HID, HID, K2P, fW, out0);
}

// Round 7
// 261.079 us; speedup vs baseline: 2.2823x; 1.0113x over previous
//
#include <hip/hip_runtime.h>
#include <hip/hip_bf16.h>

// DeepFM constants
#define BATCH 16384
#define FIELD 39
#define EMB 32
#define DIN 1248               // FIELD*EMB
#define K1P 1280               // padded K for GEMM1 (10*128)
#define HID 400
#define K2P 448                // padded K for GEMM2 (7*64)
#define NPAD 512               // padded N for both GEMMs

typedef __attribute__((ext_vector_type(8))) short short8;     // 8 bf16 = 4 VGPRs
typedef __attribute__((ext_vector_type(16))) float float16v;  // 32x32 MFMA C/D
typedef __attribute__((ext_vector_type(4))) float float4c;    // clang vec (nontemporal ok)

static __device__ __forceinline__ unsigned short f2bf(float f) {
    __hip_bfloat16 h = __float2bfloat16(f);  // RNE
    return *(unsigned short*)&h;
}

// ---------------------------------------------------------------------------
// Kernel 1 (prep): block-range-split combo.
//   blocks [0, 4096): wave-per-row gather: emb (bf16, stride K1P, zero-padded),
//     first_order, second_order, AND out0[r] = fb + fo.fW + so.fW.
//   blocks [4096, ...): weight cvt fp32->bf16 with zero padding.
// ---------------------------------------------------------------------------
#define CVT_ELEMS (NPAD * K1P + NPAD * K2P + 2 * NPAD)
#define GATHER_BLOCKS (BATCH / 4)

__global__ __launch_bounds__(256) void prep_kernel(
    const int* __restrict__ feat_index,
    const float* __restrict__ feat_value,
    const float* __restrict__ emb_table,
    const float* __restrict__ bias_table,
    const float* __restrict__ W1, const float* __restrict__ b1,
    const float* __restrict__ W2, const float* __restrict__ b2,
    const float* __restrict__ fW, const float* __restrict__ fb,
    unsigned short* __restrict__ emb_ws,   // BATCH x K1P (bf16)
    unsigned short* __restrict__ W1b,      // NPAD x K1P
    unsigned short* __restrict__ W2b,      // NPAD x K2P
    float* __restrict__ b1p, float* __restrict__ b2p,
    float* __restrict__ first_order,       // BATCH x FIELD
    float* __restrict__ second_order,      // BATCH x EMB
    float* __restrict__ out0)              // BATCH
{
    if (blockIdx.x < GATHER_BLOCKS) {
        const int lane = threadIdx.x & 63;
        const int wave = threadIdx.x >> 6;
        const int r = blockIdx.x * 4 + wave;

        int   idx0 = 0;
        float val0 = 0.f;
        float s1 = 0.f;
        if (lane < FIELD) {
            idx0 = feat_index[r * FIELD + lane];
            val0 = feat_value[r * FIELD + lane];
            float fov = bias_table[idx0] * val0;
            __builtin_nontemporal_store(fov, first_order + r * FIELD + lane);
            s1 = fov * fW[lane];
        }

        const int fsub = lane >> 3;
        const int j4   = (lane & 7) * 4;

        float sx = 0.f, sy = 0.f, sz = 0.f, sw = 0.f;
        float qx = 0.f, qy = 0.f, qz = 0.f, qw = 0.f;

        #pragma unroll
        for (int step = 0; step < 5; ++step) {
            const int   f  = step * 8 + fsub;
            const int   fi = __shfl(idx0, f, 64);
            const float fv = __shfl(val0, f, 64);
            float4 e4 = make_float4(0.f, 0.f, 0.f, 0.f);
            if (f < FIELD) {
                float4 t = *(const float4*)(emb_table + (size_t)fi * EMB + j4);
                e4.x = t.x * fv; e4.y = t.y * fv; e4.z = t.z * fv; e4.w = t.w * fv;
                uint2 pk;
                pk.x = (unsigned)f2bf(e4.x) | ((unsigned)f2bf(e4.y) << 16);
                pk.y = (unsigned)f2bf(e4.z) | ((unsigned)f2bf(e4.w) << 16);
                *(uint2*)(emb_ws + (size_t)r * K1P + step * 256 + lane * 4) = pk;
            }
            sx += e4.x; sy += e4.y; sz += e4.z; sw += e4.w;
            qx += e4.x * e4.x; qy += e4.y * e4.y; qz += e4.z * e4.z; qw += e4.w * e4.w;
        }

        if (lane < 8) {
            uint2 z; z.x = 0u; z.y = 0u;
            *(uint2*)(emb_ws + (size_t)r * K1P + DIN + lane * 4) = z;
        }

        #pragma unroll
        for (int d = 8; d < 64; d <<= 1) {
            sx += __shfl_xor(sx, d, 64); sy += __shfl_xor(sy, d, 64);
            sz += __shfl_xor(sz, d, 64); sw += __shfl_xor(sw, d, 64);
            qx += __shfl_xor(qx, d, 64); qy += __shfl_xor(qy, d, 64);
            qz += __shfl_xor(qz, d, 64); qw += __shfl_xor(qw, d, 64);
        }

        float s2 = 0.f;
        if (lane < 8) {
            float4c so4;
            so4.x = 0.5f * (sx * sx - qx);
            so4.y = 0.5f * (sy * sy - qy);
            so4.z = 0.5f * (sz * sz - qz);
            so4.w = 0.5f * (sw * sw - qw);
            __builtin_nontemporal_store(so4,
                (float4c*)(second_order + (size_t)r * EMB + lane * 4));
            const float* fw = fW + FIELD + lane * 4;
            s2 = so4.x * fw[0] + so4.y * fw[1] + so4.z * fw[2] + so4.w * fw[3];
        }

        float s = s1 + s2;
        #pragma unroll
        for (int d = 1; d < 64; d <<= 1)
            s += __shfl_xor(s, d, 64);
        if (lane == 0)
            out0[r] = s + fb[0];
    } else {
        int i = (blockIdx.x - GATHER_BLOCKS) * 256 + threadIdx.x;
        const int n1p = NPAD * K1P;
        const int n2p = NPAD * K2P;
        if (i < n1p) {
            int row = i / K1P, col = i - row * K1P;
            W1b[i] = (row < HID && col < DIN)
                   ? f2bf(W1[row * DIN + col]) : (unsigned short)0;
        } else if (i < n1p + n2p) {
            int j = i - n1p;
            int row = j / K2P, col = j - row * K2P;
            W2b[j] = (row < HID && col < HID)
                   ? f2bf(W2[row * HID + col]) : (unsigned short)0;
        } else if (i < n1p + n2p + NPAD) {
            int k = i - n1p - n2p;
            b1p[k] = (k < HID) ? b1[k] : 0.f;
        } else if (i < n1p + n2p + 2 * NPAD) {
            int k = i - n1p - n2p - NPAD;
            b2p[k] = (k < HID) ? b2[k] : 0.f;
        }
    }
}

// ---------------------------------------------------------------------------
// MFMA NT-GEMM on v_mfma_f32_32x32x16_bf16 (2382-2495 TF ceiling vs 2075 for
// 16x16x32 -- 18% cheaper issue for identical LDS traffic).
// Templated BK (128 GEMM1 / 64 GEMM2), m97-pattern gll staging, XOR chunk
// swizzle. C = relu(A * Bw^T + bias); Bw is NPAD x K padded/guard-free.
// Per wave: 64x64 = 2x2 tiles of 32x32; acc = 4 x float16v.
// Layouts (m74/m101-verified): A: m=lane&31, k=(lane>>5)*8+j; B mirrored;
// C/D: col=lane&31, row=(reg&3)+8*(reg>>2)+4*(lane>>5).
// Dead-wave skip for cols >= stn; FINAL_DOT fuses C-row . fW into out0.
// ---------------------------------------------------------------------------
template<int BK, bool OUT_BF16, bool FINAL_DOT>
__global__ __launch_bounds__(256) void gemm_mfma(
    const unsigned short* __restrict__ A, int lda,
    const unsigned short* __restrict__ Bw, int ldb,
    const float* __restrict__ bias,
    void* __restrict__ Cp, int ldc, int stn, int K,
    const float* __restrict__ fW, float* __restrict__ out0)
{
    constexpr int BM = 128, BN = 128;
    constexpr int CH  = BK / 8;            // 16B chunks per LDS row
    constexpr int RPS = 512 / BK;          // rows per 1KB gll segment
    constexpr int PASSES = BM * BK / 2048; // gll passes per side
    __shared__ __align__(16) unsigned short As[BM * BK];
    __shared__ __align__(16) unsigned short Bs[BN * BK];
    __shared__ float part[2][BM];

    const int tid  = threadIdx.x;
    const int wave = tid >> 6;
    const int lane = tid & 63;
    const int half = lane >> 5;            // 0,1
    const int l31  = lane & 31;
    const int wm = (wave & 1) * 64;
    const int wn = (wave >> 1) * 64;
    const int m0 = blockIdx.x * BM;
    const int n0 = blockIdx.y * BN;

    // staging geometry: 1KB segments, CH lanes per row, XOR chunk swizzle
    const int lr   = lane / CH;            // row within segment
    const int slot = lane % CH;            // physical 16B chunk slot

    const bool waveDead = (wave >= 2) && (n0 + 64 >= stn);

    float16v acc[2][2];
    #pragma unroll
    for (int i = 0; i < 2; ++i)
        #pragma unroll
        for (int j = 0; j < 2; ++j)
            acc[i][j] = (float16v)(0.f);

    for (int k0 = 0; k0 < K; k0 += BK) {
        #pragma unroll
        for (int p = 0; p < PASSES; ++p) {
            const int seg = wave * PASSES + p;
            const int r   = seg * RPS + lr;
            const int c   = slot ^ (r & (CH - 1));
            const unsigned short* gA = A + (size_t)(m0 + r) * lda + k0 + c * 8;
            unsigned short* lA = As + seg * 512 + lane * 8;
            __builtin_amdgcn_global_load_lds(
                (const __attribute__((address_space(1))) unsigned int*)gA,
                (__attribute__((address_space(3))) unsigned int*)lA, 16, 0, 0);
            if (!waveDead) {
                const unsigned short* gB = Bw + (size_t)(n0 + r) * ldb + k0 + c * 8;
                unsigned short* lB = Bs + seg * 512 + lane * 8;
                __builtin_amdgcn_global_load_lds(
                    (const __attribute__((address_space(1))) unsigned int*)gB,
                    (__attribute__((address_space(3))) unsigned int*)lB, 16, 0, 0);
            }
        }
        __syncthreads();

        if (!waveDead) {
            #pragma unroll
            for (int s = 0; s < BK / 16; ++s) {
                const int gch = s * 2 + half;   // global 16B chunk of fragment
                short8 af[2], bf[2];
                #pragma unroll
                for (int i = 0; i < 2; ++i) {
                    const int row = wm + i * 32 + l31;
                    af[i] = *(const short8*)(As + row * BK
                                             + ((gch ^ (row & (CH - 1))) * 8));
                }
                #pragma unroll
                for (int j = 0; j < 2; ++j) {
                    const int row = wn + j * 32 + l31;
                    bf[j] = *(const short8*)(Bs + row * BK
                                             + ((gch ^ (row & (CH - 1))) * 8));
                }
                #pragma unroll
                for (int i = 0; i < 2; ++i)
                    #pragma unroll
                    for (int j = 0; j < 2; ++j)
                        acc[i][j] = __builtin_amdgcn_mfma_f32_32x32x16_bf16(
                            af[i], bf[j], acc[i][j], 0, 0, 0);
            }
        }
        __syncthreads();
    }

    // epilogue: bias + relu + store (cols < stn); relu'd values kept in acc
    #pragma unroll
    for (int j = 0; j < 2; ++j) {
        const int col = n0 + wn + j * 32 + l31;
        const bool cok = (col < stn);
        const float bv = cok ? bias[col] : 0.f;
        #pragma unroll
        for (int i = 0; i < 2; ++i) {
            #pragma unroll
            for (int reg = 0; reg < 16; ++reg) {
                const int row = m0 + wm + i * 32
                              + (reg & 3) + 8 * (reg >> 2) + 4 * half;
                float v = acc[i][j][reg] + bv;
                v = v > 0.f ? v : 0.f;
                acc[i][j][reg] = v;
                if (cok) {
                    if (OUT_BF16)
                        ((unsigned short*)Cp)[(size_t)row * ldc + col] = f2bf(v);
                    else  // dy never re-read on device
                        __builtin_nontemporal_store(
                            v, ((float*)Cp) + (size_t)row * ldc + col);
                }
            }
        }
    }

    if (FINAL_DOT) {
        const int col0 = n0 + wn + l31;
        const int col1 = col0 + 32;
        const float fwv0 = (col0 < HID) ? fW[FIELD + EMB + col0] : 0.f;
        const float fwv1 = (col1 < HID) ? fW[FIELD + EMB + col1] : 0.f;
        #pragma unroll
        for (int i = 0; i < 2; ++i) {
            #pragma unroll
            for (int reg = 0; reg < 16; ++reg) {
                float s = acc[i][0][reg] * fwv0 + acc[i][1][reg] * fwv1;
                s += __shfl_xor(s, 1, 64);  s += __shfl_xor(s, 2, 64);
                s += __shfl_xor(s, 4, 64);  s += __shfl_xor(s, 8, 64);
                s += __shfl_xor(s, 16, 64);
                if (l31 == 0)
                    part[wn >> 6][wm + i * 32
                                  + (reg & 3) + 8 * (reg >> 2) + 4 * half] = s;
            }
        }
        __syncthreads();
        if (tid < BM)
            atomicAdd(out0 + m0 + tid, part[0][tid] + part[1][tid]);
    }
}

// ---------------------------------------------------------------------------
extern "C" void kernel_launch(void* const* d_in, const int* in_sizes, int n_in,
                              void* d_out, int out_size, void* d_ws, size_t ws_size,
                              hipStream_t stream)
{
    const int*   feat_index = (const int*)d_in[0];
    const float* feat_value = (const float*)d_in[1];
    const float* emb_table  = (const float*)d_in[2];
    const float* bias_table = (const float*)d_in[3];
    const float* W1         = (const float*)d_in[4];
    const float* b1         = (const float*)d_in[5];
    const float* W2         = (const float*)d_in[6];
    const float* b2         = (const float*)d_in[7];
    const float* fW         = (const float*)d_in[8];
    const float* fb         = (const float*)d_in[9];

    float* out = (float*)d_out;
    float* out0 = out;
    float* fo   = out + BATCH;
    float* so   = out + (size_t)BATCH * (1 + FIELD);
    float* dy   = out + (size_t)BATCH * (1 + FIELD + EMB);

    // workspace layout (bf16 element counts; all 16B-aligned):
    unsigned short* emb_ws = (unsigned short*)d_ws;                 // B x 1280
    unsigned short* h1     = emb_ws + (size_t)BATCH * K1P;          // B x 448
    unsigned short* W1b    = h1 + (size_t)BATCH * K2P;              // 512 x 1280
    unsigned short* W2b    = W1b + (size_t)NPAD * K1P;              // 512 x 448
    float*          b1p    = (float*)(W2b + (size_t)NPAD * K2P);    // 512
    float*          b2p    = b1p + NPAD;                            // 512

    const int cvt_blocks = (CVT_ELEMS + 255) / 256;
    prep_kernel<<<GATHER_BLOCKS + cvt_blocks, 256, 0, stream>>>(
        feat_index, feat_value, emb_table, bias_table,
        W1, b1, W2, b2, fW, fb,
        emb_ws, W1b, W2b, b1p, b2p, fo, so, out0);

    dim3 grid_g(BATCH / 128, NPAD / 128);  // 128 x 4
    // GEMM1: h1 = relu(emb @ W1^T + b1) -> bf16 at stride K2P; cols 400..447
    // come out exactly 0 (zero-padded weights/bias) = K2 padding for GEMM2.
    gemm_mfma<128, true, false><<<grid_g, 256, 0, stream>>>(
        emb_ws, K1P, W1b, K1P, b1p, h1, K2P, K2P, K1P, nullptr, nullptr);
    // GEMM2: dy = relu(h1 @ W2^T + b2) -> fp32 (nontemporal) + fused final dot
    gemm_mfma<64, false, true><<<grid_g, 256, 0, stream>>>(
        h1, K2P, W2b, K2P, b2p, dy, HID, HID, K2P, fW, out0);
}